// Round 19
// baseline (96.527 us; speedup 1.0000x reference)
//
#include <hip/hip_runtime.h>
#include <math.h>

// MoE router: logits = x @ gate_w  (M=32768, K=2048, N=64 fp32)
// Split-precision MFMA: x,w -> 2 fp16 limbs each; logits = xh*wh + xh*wl + xl*wh.
// Scaling: x*64, w*256 (denormal safety), descale 2^-14 at epilogue.
// R19: true 16-waves/CU test. BM=16, mt=1 (acc 16 + A-2set 16 + B-1set 32
//      ~= 95-110 VGPR, fits the 128 cap honestly), launch_bounds(256,4).
//      Grid 2048, 1024 co-resident -> exactly 2 phases, no ragged tail.
//      Pipeline = R15-proven ordering (A 2-set rotation, B single set).
// outputs (concat flat, read back as float32):
//   [0 .. 2N)   top_k_weights [N,2]
//   [2N .. 4N)  top_k_indices [N,2] (as float values)
//   [4N]        load_balance_loss scalar
#define N_TOKENS 32768
#define HIDDEN   2048
#define NEXP     64
#define BM 16                   // tokens per block
#define NWAVE 4                 // 256 threads; wave wv owns K-quarter wv
#define NBLK (N_TOKENS / BM)    // 2048
#define KSTEP 32
#define NSTEP 16                // K-quarter (512) / KSTEP
#define XSCALE 64.f
#define WSCALE 256.f
#define DESCALE (1.f / 16384.f)
#define NG 64                   // finalize stage-1 blocks (32 router-blocks each)

typedef __attribute__((ext_vector_type(8))) _Float16 half8;
typedef __attribute__((ext_vector_type(4))) float f32x4;

// ---- kernel 0: split gate_w into 2 fp16 limb planes, MFMA-fragment-packed ----
// plane order: [(S*4 + nt)*64 + lane]*8 + j  <=>  w[32S + (lane>>4)*8 + j][nt*16 + (lane&15)]
__global__ void wsplit_kernel(const float* __restrict__ gw,
                              _Float16* __restrict__ wh, _Float16* __restrict__ wl) {
    __shared__ float tile[KSTEP * NEXP];     // 32 k-rows x 64 experts
    const int S   = blockIdx.x;              // 0..63 K-steps
    const int tid = threadIdx.x;             // 256
    const float4* g4 = reinterpret_cast<const float4*>(gw + (size_t)S * KSTEP * NEXP);
    float4* t4 = reinterpret_cast<float4*>(tile);
    t4[tid]       = g4[tid];
    t4[tid + 256] = g4[tid + 256];
    __syncthreads();
    const int nt  = tid >> 6;
    const int l   = tid & 63;
    const int col = nt * 16 + (l & 15);
    const int kr  = (l >> 4) * 8;
    half8 vh, vl;
    #pragma unroll
    for (int j = 0; j < 8; ++j) {
        const float w = tile[(kr + j) * NEXP + col] * WSCALE;
        const _Float16 hh = (_Float16)w;
        vh[j] = hh;
        vl[j] = (_Float16)(w - (float)hh);
    }
    const size_t off = ((size_t)(S * 4 + nt) * 64 + l) * 8;
    *reinterpret_cast<half8*>(wh + off) = vh;
    *reinterpret_cast<half8*>(wl + off) = vl;
}

__global__ __launch_bounds__(256, 4)
void router_main(const float* __restrict__ x,
                 const _Float16* __restrict__ whp, const _Float16* __restrict__ wlp,
                 float* __restrict__ out_w, float* __restrict__ out_i,
                 float* __restrict__ wsP, int* __restrict__ wsC)
{
    __shared__ float part[NWAVE][BM][65];   // K-quarter partial logits (16.6 KB)
    __shared__ float pred[NWAVE][NEXP];
    __shared__ int   cntl[NEXP];

    const int tid  = threadIdx.x;
    const int lane = tid & 63;
    const int wv   = tid >> 6;         // 0..3 = K-quarter id
    const int m0   = blockIdx.x * BM;
    if (tid < NEXP) cntl[tid] = 0;

    const int mrow = lane & 15;        // token row within m-tile
    const int kq   = lane >> 4;        // k quad
    const int Sb   = wv * NSTEP;       // global K-step base for this wave

    const float* xb = x + (size_t)(m0 + mrow) * HIDDEN + (size_t)wv * 512 + kq * 8;

    f32x4 a[2][2];                     // [set][half-of-8] — A 2-set rotation
    half8 bh[4], bl[4];                // [nt]             — B single set
    f32x4 acc[4];
    const f32x4 zero = {0.f, 0.f, 0.f, 0.f};
    #pragma unroll
    for (int nt = 0; nt < 4; ++nt) acc[nt] = zero;

    #define LOADA(SET, s_) {                                                          \
        const float* g_ = xb + (s_) * KSTEP;                                          \
        a[SET][0] = *reinterpret_cast<const f32x4*>(g_);                              \
        a[SET][1] = *reinterpret_cast<const f32x4*>(g_ + 4);                          \
    }
    #define LOADB(s_) {                                                               \
        const int S_ = Sb + (s_);                                                     \
        _Pragma("unroll")                                                             \
        for (int nt = 0; nt < 4; ++nt) {                                              \
            const size_t o_ = ((size_t)(S_ * 4 + nt) * 64 + lane) * 8;                \
            bh[nt] = *reinterpret_cast<const half8*>(whp + o_);                       \
            bl[nt] = *reinterpret_cast<const half8*>(wlp + o_);                       \
        } }
    #define COMPUTE(AS) {                                                             \
        half8 ah, al;                                                                 \
        _Pragma("unroll")                                                             \
        for (int h = 0; h < 2; ++h)                                                   \
            _Pragma("unroll")                                                         \
            for (int j = 0; j < 4; ++j) {                                             \
                const float v_ = a[AS][h][j] * XSCALE;                                \
                const _Float16 hh_ = (_Float16)v_;                                    \
                ah[h * 4 + j] = hh_;                                                  \
                al[h * 4 + j] = (_Float16)(v_ - (float)hh_);                          \
            }                                                                         \
        _Pragma("unroll")                                                             \
        for (int nt = 0; nt < 4; ++nt) {                                              \
            f32x4 c_ = acc[nt];                                                       \
            c_ = __builtin_amdgcn_mfma_f32_16x16x32_f16(ah, bh[nt], c_, 0, 0, 0);     \
            c_ = __builtin_amdgcn_mfma_f32_16x16x32_f16(ah, bl[nt], c_, 0, 0, 0);     \
            c_ = __builtin_amdgcn_mfma_f32_16x16x32_f16(al, bh[nt], c_, 0, 0, 0);     \
            acc[nt] = c_;                                                             \
        } }

    // prologue: A set 0 and B <- step 0
    LOADA(0, 0); LOADB(0);

    // steady state (R15-proven ordering): A set reloaded only AFTER its COMPUTE;
    // B (single set) reloaded right after the COMPUTE that consumed it.
    for (int t = 0; t < NSTEP / 2; ++t) {
        const int s = t * 2;
        LOADA(1, s + 1);
        COMPUTE(0);                                    // step s
        LOADB(s + 1);
        if (s + 2 < NSTEP) LOADA(0, s + 2);
        COMPUTE(1);                                    // step s+1
        if (s + 2 < NSTEP) LOADB(s + 2);
    }
    #undef LOADA
    #undef LOADB
    #undef COMPUTE

    // dump K-quarter partials: C/D layout col=lane&15 (expert), row=(lane>>4)*4+r (token)
    #pragma unroll
    for (int nt = 0; nt < 4; ++nt)
        #pragma unroll
        for (int r = 0; r < 4; ++r)
            part[wv][(lane >> 4) * 4 + r][nt * 16 + (lane & 15)] =
                acc[nt][r] * DESCALE;
    __syncthreads();

    // epilogue: wave wv handles tokens wv*4..+3; lane = expert
    float sumP = 0.f;
    for (int t = 0; t < BM / NWAVE; ++t) {
        const int m = wv * (BM / NWAVE) + t;
        const float l = part[0][m][lane] + part[1][m][lane]
                      + part[2][m][lane] + part[3][m][lane];

        // top-1 (max value, lowest index on tie — matches jax.lax.top_k)
        float v = l; int idx = lane;
        #pragma unroll
        for (int off = 32; off >= 1; off >>= 1) {
            float ov = __shfl_xor(v, off);
            int   oi = __shfl_xor(idx, off);
            if (ov > v || (ov == v && oi < idx)) { v = ov; idx = oi; }
        }
        const float v1 = v; const int i1 = idx;
        // top-2
        v = (lane == i1) ? -INFINITY : l;
        idx = lane;
        #pragma unroll
        for (int off = 32; off >= 1; off >>= 1) {
            float ov = __shfl_xor(v, off);
            int   oi = __shfl_xor(idx, off);
            if (ov > v || (ov == v && oi < idx)) { v = ov; idx = oi; }
        }
        const float v2 = v; const int i2 = idx;
        // softmax over the two top logits (stable: v2 - v1 <= 0)
        const float ed  = expf(v2 - v1);
        const float wt1 = 1.f / (1.f + ed);
        const float wt2 = ed / (1.f + ed);
        // full softmax over 64 experts (max is v1)
        const float p = expf(l - v1);
        float Z = p;
        #pragma unroll
        for (int off = 32; off >= 1; off >>= 1) Z += __shfl_xor(Z, off);
        sumP += p / Z;
        if (lane == 0) {
            const size_t o = (size_t)(m0 + m) * 2;
            out_w[o]     = wt1;
            out_w[o + 1] = wt2;
            out_i[o]     = (float)i1;
            out_i[o + 1] = (float)i2;
            atomicAdd(&cntl[i1], 1);
            atomicAdd(&cntl[i2], 1);
        }
    }
    pred[wv][lane] = sumP;
    __syncthreads();
    if (tid < NEXP) {
        float s = 0.f;
        #pragma unroll
        for (int w2 = 0; w2 < NWAVE; ++w2) s += pred[w2][tid];
        wsP[(size_t)blockIdx.x * NEXP + tid] = s;
        wsC[(size_t)blockIdx.x * NEXP + tid] = cntl[tid];
    }
}

// ---- finalize stage 1: 64 blocks x 1 wave; block g sums router-blocks g*32..g*32+31 ----
__global__ void router_fin1(const float* __restrict__ wsP, const int* __restrict__ wsC,
                            float* __restrict__ Ps1, float* __restrict__ Cs1)
{
    const int g = blockIdx.x;          // 0..63
    const int e = threadIdx.x;         // 64 threads, lane = expert
    float P = 0.f, C = 0.f;
    #pragma unroll
    for (int r = 0; r < NBLK / NG; ++r) {
        const size_t row = (size_t)(g * (NBLK / NG) + r) * NEXP + e;
        P += wsP[row];
        C += (float)wsC[row];
    }
    Ps1[(size_t)g * NEXP + e] = P;
    Cs1[(size_t)g * NEXP + e] = C;
}

// ---- finalize stage 2: 1 block x 1 wave; combine 64 partials, compute loss ----
__global__ void router_fin2(const float* __restrict__ Ps1, const float* __restrict__ Cs1,
                            float* __restrict__ out_loss)
{
    const int e = threadIdx.x;         // 64 threads
    float P = 0.f, C = 0.f;
    #pragma unroll
    for (int g = 0; g < NG; ++g) {
        P += Ps1[(size_t)g * NEXP + e];
        C += Cs1[(size_t)g * NEXP + e];
    }
    float val = (C / (float)N_TOKENS) * (P / (float)N_TOKENS);
    #pragma unroll
    for (int off = 32; off >= 1; off >>= 1) val += __shfl_xor(val, off);
    if (e == 0) out_loss[0] = (float)NEXP * val;
}

extern "C" void kernel_launch(void* const* d_in, const int* in_sizes, int n_in,
                              void* d_out, int out_size, void* d_ws, size_t ws_size,
                              hipStream_t stream) {
    const float* x  = (const float*)d_in[0];
    const float* gw = (const float*)d_in[1];
    float* out   = (float*)d_out;
    float* out_w = out;                        // [N,2] weights
    float* out_i = out + (size_t)N_TOKENS * 2; // [N,2] indices (as floats)
    float* loss  = out + (size_t)N_TOKENS * 4; // scalar
    float*    wsP = (float*)d_ws;                                    // 512 KB (2048x64 f32)
    int*      wsC = (int*)((char*)d_ws + 524288);                    // 512 KB
    _Float16* wh  = (_Float16*)((char*)d_ws + 1048576);              // 256 KB
    _Float16* wl  = wh + (size_t)HIDDEN * NEXP;                      // 256 KB
    float*    Ps1 = (float*)((char*)d_ws + 1572864);                 // 16 KB
    float*    Cs1 = Ps1 + NG * NEXP;                                 // 16 KB
    hipLaunchKernelGGL(wsplit_kernel, dim3(HIDDEN / KSTEP), dim3(256), 0, stream, gw, wh, wl);
    hipLaunchKernelGGL(router_main, dim3(NBLK), dim3(256), 0, stream,
                       x, wh, wl, out_w, out_i, wsP, wsC);
    hipLaunchKernelGGL(router_fin1, dim3(NG), dim3(64), 0, stream, wsP, wsC, Ps1, Cs1);
    hipLaunchKernelGGL(router_fin2, dim3(1), dim3(64), 0, stream, Ps1, Cs1, loss);
}

// Round 20
// 82.016 us; speedup vs baseline: 1.1769x; 1.1769x over previous
//
#include <hip/hip_runtime.h>
#include <math.h>

// MoE router: logits = x @ gate_w  (M=32768, K=2048, N=64 fp32)
// Split-precision MFMA: x,w -> 2 fp16 limbs each; logits = xh*wh + xh*wl + xl*wh.
// Scaling: x*64, w*256 (denormal safety), descale 2^-14 at epilogue.
// R20 (FINAL): restore of R14/R18 — best measured config (82.06-82.35 us).
//   BM=32, 256-thr blocks, wave = 32 tokens (mt=2) x 64 experts x K-quarter,
//   A/B 2-set register rotation (a set is reloaded only AFTER its consuming
//   COMPUTE — the collision-free invariant), launch_bounds(256,3) -> ~156 VGPR
//   honored -> 12 waves/CU. Measured optimum of the occupancy x B-traffic
//   tradeoff: (BM=64,8w)=91.9, (BM=32,12w)=82.1, (BM=16,16w)=96.5.
// outputs (concat flat, read back as float32):
//   [0 .. 2N)   top_k_weights [N,2]
//   [2N .. 4N)  top_k_indices [N,2] (as float values)
//   [4N]        load_balance_loss scalar
#define N_TOKENS 32768
#define HIDDEN   2048
#define NEXP     64
#define BM 32                   // tokens per block
#define NWAVE 4                 // 256 threads; wave wv owns K-quarter wv
#define NBLK (N_TOKENS / BM)    // 1024
#define KSTEP 32
#define NSTEP 16                // K-quarter (512) / KSTEP
#define XSCALE 64.f
#define WSCALE 256.f
#define DESCALE (1.f / 16384.f)
#define NG 64                   // finalize stage-1 blocks (16 router-blocks each)

typedef __attribute__((ext_vector_type(8))) _Float16 half8;
typedef __attribute__((ext_vector_type(4))) float f32x4;

// ---- kernel 0: split gate_w into 2 fp16 limb planes, MFMA-fragment-packed ----
// plane order: [(S*4 + nt)*64 + lane]*8 + j  <=>  w[32S + (lane>>4)*8 + j][nt*16 + (lane&15)]
__global__ void wsplit_kernel(const float* __restrict__ gw,
                              _Float16* __restrict__ wh, _Float16* __restrict__ wl) {
    __shared__ float tile[KSTEP * NEXP];     // 32 k-rows x 64 experts
    const int S   = blockIdx.x;              // 0..63 K-steps
    const int tid = threadIdx.x;             // 256
    const float4* g4 = reinterpret_cast<const float4*>(gw + (size_t)S * KSTEP * NEXP);
    float4* t4 = reinterpret_cast<float4*>(tile);
    t4[tid]       = g4[tid];
    t4[tid + 256] = g4[tid + 256];
    __syncthreads();
    const int nt  = tid >> 6;
    const int l   = tid & 63;
    const int col = nt * 16 + (l & 15);
    const int kr  = (l >> 4) * 8;
    half8 vh, vl;
    #pragma unroll
    for (int j = 0; j < 8; ++j) {
        const float w = tile[(kr + j) * NEXP + col] * WSCALE;
        const _Float16 hh = (_Float16)w;
        vh[j] = hh;
        vl[j] = (_Float16)(w - (float)hh);
    }
    const size_t off = ((size_t)(S * 4 + nt) * 64 + l) * 8;
    *reinterpret_cast<half8*>(wh + off) = vh;
    *reinterpret_cast<half8*>(wl + off) = vl;
}

__global__ __launch_bounds__(256, 3)
void router_main(const float* __restrict__ x,
                 const _Float16* __restrict__ whp, const _Float16* __restrict__ wlp,
                 float* __restrict__ out_w, float* __restrict__ out_i,
                 float* __restrict__ wsP, int* __restrict__ wsC)
{
    __shared__ float part[NWAVE][BM][65];   // K-quarter partial logits (33.3 KB)
    __shared__ float pred[NWAVE][NEXP];
    __shared__ int   cntl[NEXP];

    const int tid  = threadIdx.x;
    const int lane = tid & 63;
    const int wv   = tid >> 6;         // 0..3 = K-quarter id
    const int m0   = blockIdx.x * BM;
    if (tid < NEXP) cntl[tid] = 0;

    const int mrow = lane & 15;        // token row within m-tile
    const int kq   = lane >> 4;        // k quad
    const int Sb   = wv * NSTEP;       // global K-step base for this wave

    const float* xb = x + (size_t)(m0 + mrow) * HIDDEN + (size_t)wv * 512 + kq * 8;

    f32x4 a[2][2][2];                  // [set][mt][half-of-8]
    half8 bh[2][4], bl[2][4];          // [set][nt]
    f32x4 acc[2][4];
    const f32x4 zero = {0.f, 0.f, 0.f, 0.f};
    #pragma unroll
    for (int mt = 0; mt < 2; ++mt)
        #pragma unroll
        for (int nt = 0; nt < 4; ++nt) acc[mt][nt] = zero;

    #define LOADA(SET, s_) {                                                          \
        _Pragma("unroll")                                                             \
        for (int mt = 0; mt < 2; ++mt) {                                              \
            const float* g_ = xb + (size_t)mt * (16 * HIDDEN) + (s_) * KSTEP;         \
            a[SET][mt][0] = *reinterpret_cast<const f32x4*>(g_);                      \
            a[SET][mt][1] = *reinterpret_cast<const f32x4*>(g_ + 4);                  \
        } }
    #define LOADB(SET, s_) {                                                          \
        const int S_ = Sb + (s_);                                                     \
        _Pragma("unroll")                                                             \
        for (int nt = 0; nt < 4; ++nt) {                                              \
            const size_t o_ = ((size_t)(S_ * 4 + nt) * 64 + lane) * 8;                \
            bh[SET][nt] = *reinterpret_cast<const half8*>(whp + o_);                  \
            bl[SET][nt] = *reinterpret_cast<const half8*>(wlp + o_);                  \
        } }
    #define COMPUTE(AS, BS) {                                                         \
        half8 ah[2], al[2];                                                           \
        _Pragma("unroll")                                                             \
        for (int mt = 0; mt < 2; ++mt)                                                \
            _Pragma("unroll")                                                         \
            for (int h = 0; h < 2; ++h)                                               \
                _Pragma("unroll")                                                     \
                for (int j = 0; j < 4; ++j) {                                         \
                    const float v_ = a[AS][mt][h][j] * XSCALE;                        \
                    const _Float16 hh_ = (_Float16)v_;                                \
                    ah[mt][h * 4 + j] = hh_;                                          \
                    al[mt][h * 4 + j] = (_Float16)(v_ - (float)hh_);                  \
                }                                                                     \
        _Pragma("unroll")                                                             \
        for (int mt = 0; mt < 2; ++mt)                                                \
            _Pragma("unroll")                                                         \
            for (int nt = 0; nt < 4; ++nt) {                                          \
                f32x4 c_ = acc[mt][nt];                                               \
                c_ = __builtin_amdgcn_mfma_f32_16x16x32_f16(ah[mt], bh[BS][nt], c_, 0, 0, 0); \
                c_ = __builtin_amdgcn_mfma_f32_16x16x32_f16(ah[mt], bl[BS][nt], c_, 0, 0, 0); \
                c_ = __builtin_amdgcn_mfma_f32_16x16x32_f16(al[mt], bh[BS][nt], c_, 0, 0, 0); \
                acc[mt][nt] = c_;                                                     \
            } }

    // prologue: set 0 <- step 0
    LOADA(0, 0); LOADB(0, 0);

    // steady state: 2-step body; a set is reloaded only AFTER its COMPUTE consumes it
    for (int t = 0; t < NSTEP / 2; ++t) {
        const int s = t * 2;
        LOADA(1, s + 1); LOADB(1, s + 1);
        COMPUTE(0, 0);                                   // consumes set0 = step s
        if (s + 2 < NSTEP) { LOADA(0, s + 2); LOADB(0, s + 2); }
        COMPUTE(1, 1);                                   // consumes set1 = step s+1
    }
    #undef LOADA
    #undef LOADB
    #undef COMPUTE

    // dump K-quarter partials: C/D layout col=lane&15 (expert), row=(lane>>4)*4+r (token)
    #pragma unroll
    for (int mt = 0; mt < 2; ++mt)
        #pragma unroll
        for (int nt = 0; nt < 4; ++nt)
            #pragma unroll
            for (int r = 0; r < 4; ++r)
                part[wv][mt * 16 + (lane >> 4) * 4 + r][nt * 16 + (lane & 15)] =
                    acc[mt][nt][r] * DESCALE;
    __syncthreads();

    // epilogue: wave wv handles tokens wv*8..+7; lane = expert
    float sumP = 0.f;
    for (int t = 0; t < BM / NWAVE; ++t) {
        const int m = wv * (BM / NWAVE) + t;
        const float l = part[0][m][lane] + part[1][m][lane]
                      + part[2][m][lane] + part[3][m][lane];

        // top-1 (max value, lowest index on tie — matches jax.lax.top_k)
        float v = l; int idx = lane;
        #pragma unroll
        for (int off = 32; off >= 1; off >>= 1) {
            float ov = __shfl_xor(v, off);
            int   oi = __shfl_xor(idx, off);
            if (ov > v || (ov == v && oi < idx)) { v = ov; idx = oi; }
        }
        const float v1 = v; const int i1 = idx;
        // top-2
        v = (lane == i1) ? -INFINITY : l;
        idx = lane;
        #pragma unroll
        for (int off = 32; off >= 1; off >>= 1) {
            float ov = __shfl_xor(v, off);
            int   oi = __shfl_xor(idx, off);
            if (ov > v || (ov == v && oi < idx)) { v = ov; idx = oi; }
        }
        const float v2 = v; const int i2 = idx;
        // softmax over the two top logits (stable: v2 - v1 <= 0)
        const float ed  = expf(v2 - v1);
        const float wt1 = 1.f / (1.f + ed);
        const float wt2 = ed / (1.f + ed);
        // full softmax over 64 experts (max is v1)
        const float p = expf(l - v1);
        float Z = p;
        #pragma unroll
        for (int off = 32; off >= 1; off >>= 1) Z += __shfl_xor(Z, off);
        sumP += p / Z;
        if (lane == 0) {
            const size_t o = (size_t)(m0 + m) * 2;
            out_w[o]     = wt1;
            out_w[o + 1] = wt2;
            out_i[o]     = (float)i1;
            out_i[o + 1] = (float)i2;
            atomicAdd(&cntl[i1], 1);
            atomicAdd(&cntl[i2], 1);
        }
    }
    pred[wv][lane] = sumP;
    __syncthreads();
    if (tid < NEXP) {
        float s = 0.f;
        #pragma unroll
        for (int w2 = 0; w2 < NWAVE; ++w2) s += pred[w2][tid];
        wsP[(size_t)blockIdx.x * NEXP + tid] = s;
        wsC[(size_t)blockIdx.x * NEXP + tid] = cntl[tid];
    }
}

// ---- finalize stage 1: 64 blocks x 1 wave; block g sums router-blocks g*16..g*16+15 ----
__global__ void router_fin1(const float* __restrict__ wsP, const int* __restrict__ wsC,
                            float* __restrict__ Ps1, float* __restrict__ Cs1)
{
    const int g = blockIdx.x;          // 0..63
    const int e = threadIdx.x;         // 64 threads, lane = expert
    float P = 0.f, C = 0.f;
    #pragma unroll
    for (int r = 0; r < NBLK / NG; ++r) {
        const size_t row = (size_t)(g * (NBLK / NG) + r) * NEXP + e;
        P += wsP[row];
        C += (float)wsC[row];
    }
    Ps1[(size_t)g * NEXP + e] = P;
    Cs1[(size_t)g * NEXP + e] = C;
}

// ---- finalize stage 2: 1 block x 1 wave; combine 64 partials, compute loss ----
__global__ void router_fin2(const float* __restrict__ Ps1, const float* __restrict__ Cs1,
                            float* __restrict__ out_loss)
{
    const int e = threadIdx.x;         // 64 threads
    float P = 0.f, C = 0.f;
    #pragma unroll
    for (int g = 0; g < NG; ++g) {
        P += Ps1[(size_t)g * NEXP + e];
        C += Cs1[(size_t)g * NEXP + e];
    }
    float val = (C / (float)N_TOKENS) * (P / (float)N_TOKENS);
    #pragma unroll
    for (int off = 32; off >= 1; off >>= 1) val += __shfl_xor(val, off);
    if (e == 0) out_loss[0] = (float)NEXP * val;
}

extern "C" void kernel_launch(void* const* d_in, const int* in_sizes, int n_in,
                              void* d_out, int out_size, void* d_ws, size_t ws_size,
                              hipStream_t stream) {
    const float* x  = (const float*)d_in[0];
    const float* gw = (const float*)d_in[1];
    float* out   = (float*)d_out;
    float* out_w = out;                        // [N,2] weights
    float* out_i = out + (size_t)N_TOKENS * 2; // [N,2] indices (as floats)
    float* loss  = out + (size_t)N_TOKENS * 4; // scalar
    float*    wsP = (float*)d_ws;                                    // 256 KB (1024x64 f32)
    int*      wsC = (int*)((char*)d_ws + 262144);                    // 256 KB
    _Float16* wh  = (_Float16*)((char*)d_ws + 524288);               // 256 KB
    _Float16* wl  = wh + (size_t)HIDDEN * NEXP;                      // 256 KB
    float*    Ps1 = (float*)((char*)d_ws + 1048576);                 // 16 KB
    float*    Cs1 = Ps1 + NG * NEXP;                                 // 16 KB
    hipLaunchKernelGGL(wsplit_kernel, dim3(HIDDEN / KSTEP), dim3(256), 0, stream, gw, wh, wl);
    hipLaunchKernelGGL(router_main, dim3(NBLK), dim3(256), 0, stream,
                       x, wh, wl, out_w, out_i, wsP, wsC);
    hipLaunchKernelGGL(router_fin1, dim3(NG), dim3(64), 0, stream, wsP, wsC, Ps1, Cs1);
    hipLaunchKernelGGL(router_fin2, dim3(1), dim3(64), 0, stream, Ps1, Cs1, loss);
}